// Round 2
// baseline (20.545 us; speedup 1.0000x reference)
//
#include <hip/hip_runtime.h>

// HistByProfMultiChannel: x (16,128,56,56) f32, hist_edges (128,10) f32
// out (16,128,11) f32. One block per (bt,c); 3136 contiguous pixels reduced
// into 11 bins.
//
// R2: coefficients forced to SGPR (readfirstlane) to cut VGPR pressure;
// all 3 full float4 loads issued up front (prefetch); 16-lane tail isolated.

#define NE 10
#define NBINS 11
#define HW 3136
#define HW4 784   // HW / 4
#define NCH 128

__device__ __forceinline__ float rfl(float xv) {
    return __int_as_float(__builtin_amdgcn_readfirstlane(__float_as_int(xv)));
}

__device__ __forceinline__ void accum4(float4 p,
                                       const float* As, const float* Bs, const float* Cs,
                                       float sB, float sC, float* acc) {
    float vs[4] = {p.x, p.y, p.z, p.w};
    #pragma unroll
    for (int k = 0; k < 4; ++k) {
        float v  = vs[k];
        float v2 = v * v;
        #pragma unroll
        for (int j = 0; j < NE; ++j) {
            float arg = fmaf(As[j], v2, fmaf(Bs[j], v, Cs[j]));
            acc[j] += __builtin_amdgcn_exp2f(arg);
        }
        float den = 1.0f + __builtin_amdgcn_exp2f(fmaf(sB, v, sC));
        acc[NE] += __builtin_amdgcn_rcpf(den);
    }
}

__global__ __launch_bounds__(256, 6)
void hist_kernel(const float* __restrict__ x,
                 const float* __restrict__ edges,
                 float* __restrict__ out) {
    const int bc  = blockIdx.x;          // bt*NCH + c
    const int c   = bc & (NCH - 1);
    const int tid = threadIdx.x;

    const float LOG2E = 1.4426950408889634f;

    // Edges are block-uniform; pull through readfirstlane so downstream
    // VALU-computed coefficients can be scalarized too.
    float e[NE];
    #pragma unroll
    for (int j = 0; j < NE; ++j) e[j] = rfl(edges[c * NE + j]);

    // exp(-0.5*((v-mu)/sig)^2) = exp2(A*v^2 + B*v + C), folded with log2(e).
    float As[NE], Bs[NE], Cs[NE];
    {
        float mu  = e[0];
        float sig = (e[0] - e[1]) * (1.0f / 3.0f) + 1e-6f;
        float k   = -0.5f * LOG2E / (sig * sig);
        As[0] = rfl(k); Bs[0] = rfl(-2.0f * k * mu); Cs[0] = rfl(k * mu * mu);
    }
    #pragma unroll
    for (int j = 1; j < NE; ++j) {
        float mu  = (e[j - 1] + e[j]) * 0.5f;
        float sig = (e[j - 1] - e[j]) * (1.0f / 3.0f) + 1e-6f;
        float k   = -0.5f * LOG2E / (sig * sig);
        As[j] = rfl(k); Bs[j] = rfl(-2.0f * k * mu); Cs[j] = rfl(k * mu * mu);
    }
    // sigmoid tail: 1/(1+exp(-20*(v-e9))) = rcp(1 + exp2(sB*v + sC))
    const float sB = rfl(-20.0f * LOG2E);
    const float sC = rfl(20.0f * LOG2E * e[NE - 1]);

    float acc[NBINS];
    #pragma unroll
    for (int j = 0; j < NBINS; ++j) acc[j] = 0.0f;

    // 784 float4 per block: 3 full rounds of 256 threads + 16-lane tail.
    const float4* xp = (const float4*)(x + (size_t)bc * HW);
    float4 p0 = xp[tid];
    float4 p1 = xp[tid + 256];
    float4 p2 = xp[tid + 512];
    const bool tail = tid < (HW4 - 768);   // 16 lanes
    float4 p3 = make_float4(0.f, 0.f, 0.f, 0.f);
    if (tail) p3 = xp[768 + tid];

    accum4(p0, As, Bs, Cs, sB, sC, acc);
    accum4(p1, As, Bs, Cs, sB, sC, acc);
    accum4(p2, As, Bs, Cs, sB, sC, acc);
    if (tail) accum4(p3, As, Bs, Cs, sB, sC, acc);

    // Wave (64-lane) reduce each accumulator.
    #pragma unroll
    for (int j = 0; j < NBINS; ++j) {
        float a = acc[j];
        #pragma unroll
        for (int off = 32; off > 0; off >>= 1)
            a += __shfl_down(a, off, 64);
        acc[j] = a;
    }

    // Cross-wave reduce via LDS (4 waves x 11 bins).
    __shared__ float red[4][NBINS];
    const int wave = tid >> 6;
    const int lane = tid & 63;
    if (lane == 0) {
        #pragma unroll
        for (int j = 0; j < NBINS; ++j) red[wave][j] = acc[j];
    }
    __syncthreads();
    if (tid < NBINS) {
        float s = red[0][tid] + red[1][tid] + red[2][tid] + red[3][tid];
        out[(size_t)bc * NBINS + tid] = s;
    }
}

extern "C" void kernel_launch(void* const* d_in, const int* in_sizes, int n_in,
                              void* d_out, int out_size, void* d_ws, size_t ws_size,
                              hipStream_t stream) {
    const float* x     = (const float*)d_in[0];
    const float* edges = (const float*)d_in[1];
    float* out         = (float*)d_out;
    hist_kernel<<<dim3(16 * NCH), dim3(256), 0, stream>>>(x, edges, out);
}